// Round 13
// baseline (4830.637 us; speedup 1.0000x reference)
//
#include <hip/hip_runtime.h>

#define BDIM 64
#define TDIM 1024
#define DDIM 256
#define HDIM 512
#define RING 8

typedef unsigned short ushort_t;
typedef unsigned int uint32;
typedef unsigned long long ull;
typedef __attribute__((ext_vector_type(8))) short short8;
typedef __attribute__((ext_vector_type(4))) float f32x4;

__device__ __forceinline__ ushort_t f2bf(float f) {
  union { float f; uint32 u; } v; v.f = f;
  uint32 u = v.u;
  return (ushort_t)((u + 0x7fffu + ((u >> 16) & 1u)) >> 16);
}

__device__ __forceinline__ short8 pack8(float4 a, float4 b) {
  short8 s;
  s[0] = (short)f2bf(a.x); s[1] = (short)f2bf(a.y);
  s[2] = (short)f2bf(a.z); s[3] = (short)f2bf(a.w);
  s[4] = (short)f2bf(b.x); s[5] = (short)f2bf(b.y);
  s[6] = (short)f2bf(b.z); s[7] = (short)f2bf(b.w);
  return s;
}

__device__ __forceinline__ ull pack4bf(f32x4 v) {
  return (ull)f2bf(v[0]) | ((ull)f2bf(v[1]) << 16)
       | ((ull)f2bf(v[2]) << 32) | ((ull)f2bf(v[3]) << 48);
}

__device__ __forceinline__ float sigm(float x) { return 1.0f / (1.0f + __expf(-x)); }
__device__ __forceinline__ float tanh_fast(float x) { return 1.0f - 2.0f / (__expf(2.0f * x) + 1.0f); }

__device__ __forceinline__ uint32 ld_sc1(uint32* p) {
  return __hip_atomic_load(p, __ATOMIC_RELAXED, __HIP_MEMORY_SCOPE_AGENT);
}
__device__ __forceinline__ void st_sc1(uint32* p, uint32 v) {
  __hip_atomic_store(p, v, __ATOMIC_RELAXED, __HIP_MEMORY_SCOPE_AGENT);
}
__device__ __forceinline__ void st_sc1_u64(ull* p, ull v) {
  __hip_atomic_store(p, v, __ATOMIC_RELAXED, __HIP_MEMORY_SCOPE_AGENT);
}
__device__ __forceinline__ ull ld_sc1_u64(const ull* p) {
  return __hip_atomic_load((ull*)p, __ATOMIC_RELAXED, __HIP_MEMORY_SCOPE_AGENT);
}

// fused dual poll: lanes 0..31 watch setA[lane] >= tgtA, lanes 32..63 watch
// setB[lane-32] >= tgtB. All 4 waves run it redundantly -> no barrier needed
// between poll and the dependent loads.
__device__ __forceinline__ void poll_fused(uint32* setA, uint32 tgtA,
                                           uint32* setB, uint32 tgtB, int lane) {
  uint32* fl  = (lane < 32) ? (setA + lane) : (setB + (lane - 32));
  uint32 tgt  = (lane < 32) ? tgtA : tgtB;
  int it = 0;
  for (;;) {
    uint32 v = ld_sc1(fl);
    if (__all((int)(v >= tgt))) break;
    if (++it > 60000) break;   // bounded: wrong beats hang
  }
  asm volatile("" ::: "memory");
}

// ---- fragment-major LDS layout (conflict-free MFMA reads, r10-proven) ----
__device__ __forceinline__ int frag_off(int row, int kf, int lg) {   // ushort units
  return kf * 512 + (((lg * 16 + row) ^ (kf & 7)) << 3);
}

__device__ __forceinline__ void ds_stage(ushort_t* dst, int tid, const ull* v) {
#pragma unroll
  for (int q = 0; q < 8; ++q) {
    int idx = q * 256 + tid;
    int row = idx >> 7, inner = idx & 127;
    int kf = inner >> 3, lg = (inner >> 1) & 3, e = (inner & 1) * 4;
    *(ull*)&dst[frag_off(row, kf, lg) + e] = v[q];
  }
}

__device__ __forceinline__ void load_sc1_8(const ull* src, int tid, ull* v) {
#pragma unroll
  for (int q = 0; q < 8; ++q) v[q] = ld_sc1_u64(src + q * 256 + tid);
}

__global__ void __launch_bounds__(256, 1)
lstm_fused(const float* __restrict__ x,
           const float* __restrict__ w_ih0, const float* __restrict__ w_hh0,
           const float* __restrict__ b0,
           const float* __restrict__ w_ih1, const float* __restrict__ w_hh1,
           const float* __restrict__ b1,
           float* __restrict__ out,
           uint32* cnt0F, uint32* cnt1F, uint32* consF,
           ushort_t* ring, ushort_t* h1buf)
{
  const int b     = (int)blockIdx.x;
  const int g     = b & 7;
  const int layer = g >> 2;
  const int bt    = g & 3;
  const int ct    = b >> 3;
  const int tid   = (int)threadIdx.x;
  const int wv    = tid >> 6;
  const int lane  = tid & 63;
  const int lr    = lane & 15;
  const int lg    = lane >> 4;

  __shared__ __align__(16) ushort_t Is[16 * 512];   // fragment-major
  __shared__ __align__(16) ushort_t Hs[16 * 512];   // fragment-major
  __shared__ __align__(16) float gates[4][16][20];  // padded: 16B-aligned rows, ~2-way banks

  const int NI  = layer ? 16 : 8;
  const int Din = layer ? HDIM : DDIM;
  const float* wih = layer ? w_ih1 : w_ih0;
  const float* whh = layer ? w_hh1 : w_hh0;
  const float* bb  = layer ? b1 : b0;
  const int grow = wv * HDIM + ct * 16 + lr;

  short8 wf[32];
#pragma unroll
  for (int kf = 0; kf < 32; ++kf) wf[kf] = (short8)((short)0);
#pragma unroll
  for (int kf = 0; kf < 32; ++kf) {
    if (kf < NI + 16) {
      const float* src;
      if (kf < NI) src = wih + (size_t)grow * Din + (size_t)kf * 32 + lg * 8;
      else         src = whh + (size_t)grow * HDIM + (size_t)(kf - NI) * 32 + lg * 8;
      float4 a = *(const float4*)(src);
      float4 bq = *(const float4*)(src + 4);
      wf[kf] = pack8(a, bq);
    }
  }
  const float bias = bb[grow];

  const ull* ring_u  = (const ull*)ring;
  const ull* h1buf_u = (const ull*)h1buf;
  uint32* dummyF = consF + 128;   // zero-filled region, target 0 -> instant pass

  float c4[4] = {0.f, 0.f, 0.f, 0.f};     // wave0: 4 cell states
  float4 xp0, xp1, xp2, xp3;
  const int xr = tid >> 4;
  const int xcb = tid & 15;

  if (layer == 0) {
    const float4* xv = (const float4*)(x + (size_t)(bt * 16 + xr) * (TDIM * DDIM) + xcb * 16);
    xp0 = xv[0]; xp1 = xv[1]; xp2 = xv[2]; xp3 = xv[3];
  }

  for (int t = 0; t < TDIM; ++t) {
    // ---- P1: fused poll, all waves redundantly (no barrier after) ----
    if (layer == 0) {
      poll_fused(cnt0F + bt * 32, (uint32)t,
                 consF + bt * 32, (t >= RING) ? (uint32)(t - RING + 1) : 0u, lane);
    } else {
      poll_fused(cnt1F + bt * 32, (uint32)t,
                 cnt0F + bt * 32, (uint32)(t + 1), lane);
    }
    (void)dummyF;

    // ---- P2/P3: loads + stage ----
    if (layer == 0) {
      {
        const int c0 = xcb * 16;
        *(short8*)&Is[frag_off(xr, c0 >> 5, (c0 >> 3) & 3)] = pack8(xp0, xp1);
        const int c1 = c0 + 8;
        *(short8*)&Is[frag_off(xr, c1 >> 5, (c1 >> 3) & 3)] = pack8(xp2, xp3);
      }
      if (t > 0) {
        ull hv[8];
        load_sc1_8(ring_u + (size_t)((t - 1) & (RING - 1)) * 8192 + (size_t)bt * 2048, tid, hv);
        ds_stage(Hs, tid, hv);
      }
    } else {
      ull rv[8], hv[8];
      load_sc1_8(ring_u + (size_t)(t & (RING - 1)) * 8192 + (size_t)bt * 2048, tid, rv);
      if (t > 0)
        load_sc1_8(h1buf_u + (size_t)((t - 1) & 1) * 8192 + (size_t)bt * 2048, tid, hv);
      ds_stage(Is, tid, rv);
      if (t > 0) ds_stage(Hs, tid, hv);
    }
    __syncthreads();   // B1
    if (layer == 1 && tid == 0)
      st_sc1(consF + bt * 32 + ct, (uint32)(t + 1));   // ring slot consumed

    // ---- P5: MFMA (4 accumulators) ----
    f32x4 a0v = {0.f,0.f,0.f,0.f}, a1v = {0.f,0.f,0.f,0.f};
    f32x4 a2v = {0.f,0.f,0.f,0.f}, a3v = {0.f,0.f,0.f,0.f};
#pragma unroll
    for (int kf = 0; kf < 16; ++kf) {
      if (kf < NI) {
        const short8 af = *(const short8*)&Is[frag_off(lr, kf, lg)];
        if ((kf & 3) == 0)      a0v = __builtin_amdgcn_mfma_f32_16x16x32_bf16(af, wf[kf], a0v, 0, 0, 0);
        else if ((kf & 3) == 1) a1v = __builtin_amdgcn_mfma_f32_16x16x32_bf16(af, wf[kf], a1v, 0, 0, 0);
        else if ((kf & 3) == 2) a2v = __builtin_amdgcn_mfma_f32_16x16x32_bf16(af, wf[kf], a2v, 0, 0, 0);
        else                    a3v = __builtin_amdgcn_mfma_f32_16x16x32_bf16(af, wf[kf], a3v, 0, 0, 0);
      }
    }
    if (t > 0) {
#pragma unroll
      for (int kf = 0; kf < 16; ++kf) {
        const short8 af = *(const short8*)&Hs[frag_off(lr, kf, lg)];
        if ((kf & 3) == 0)      a0v = __builtin_amdgcn_mfma_f32_16x16x32_bf16(af, wf[NI + kf], a0v, 0, 0, 0);
        else if ((kf & 3) == 1) a1v = __builtin_amdgcn_mfma_f32_16x16x32_bf16(af, wf[NI + kf], a1v, 0, 0, 0);
        else if ((kf & 3) == 2) a2v = __builtin_amdgcn_mfma_f32_16x16x32_bf16(af, wf[NI + kf], a2v, 0, 0, 0);
        else                    a3v = __builtin_amdgcn_mfma_f32_16x16x32_bf16(af, wf[NI + kf], a3v, 0, 0, 0);
      }
    }
#pragma unroll
    for (int i = 0; i < 4; ++i) {
      float v = ((a0v[i] + a1v[i]) + (a2v[i] + a3v[i])) + bias;
      float a = (wv < 3) ? sigm(v) : tanh_fast(v);
      gates[wv][lg * 4 + i][lr] = a;
    }
    __syncthreads();   // B2

    // ---- P6/P7: pointwise (wave0, barrier-free tail) + publish; others x-prefetch ----
    if (layer == 0 && wv != 0 && t + 1 < TDIM) {
      const float4* xv = (const float4*)(x + (size_t)(bt * 16 + xr) * (TDIM * DDIM)
                                           + (size_t)(t + 1) * DDIM + xcb * 16);
      xp0 = xv[0]; xp1 = xv[1]; xp2 = xv[2]; xp3 = xv[3];
    }
    if (wv == 0) {
      const int r  = lane >> 2;
      const int cg = lane & 3;
      f32x4 gi = *(const f32x4*)&gates[0][r][cg * 4];
      f32x4 gf = *(const f32x4*)&gates[1][r][cg * 4];
      f32x4 go = *(const f32x4*)&gates[2][r][cg * 4];
      f32x4 gg = *(const f32x4*)&gates[3][r][cg * 4];
      f32x4 nh4, nc4;
#pragma unroll
      for (int k = 0; k < 4; ++k) {
        float nc = gf[k] * c4[k] + gi[k] * gg[k];
        float nh = go[k] * tanh_fast(nc);     // h uses UNCLIPPED c
        nc = fminf(fmaxf(nc, -50.f), 50.f);
        nh = fminf(fmaxf(nh, -50.f), 50.f);
        c4[k] = nc; nh4[k] = nh; nc4[k] = nc;
      }
      const ull hv = pack4bf(nh4);
      ull* dst;
      if (layer == 0)
        dst = (ull*)(ring_u + (size_t)(t & (RING - 1)) * 8192
                     + (size_t)(bt * 16 + r) * 128 + ct * 4 + cg);
      else
        dst = (ull*)(h1buf_u + (size_t)(t & 1) * 8192
                     + (size_t)(bt * 16 + r) * 128 + ct * 4 + cg);
      st_sc1_u64(dst, hv);
      asm volatile("s_waitcnt vmcnt(0)" ::: "memory");
      if (lane == 0) st_sc1((layer == 0 ? cnt0F : cnt1F) + bt * 32 + ct, (uint32)(t + 1));
      if (layer == 1)
        *(f32x4*)&out[(size_t)(bt * 16 + r) * (TDIM * HDIM) + (size_t)t * HDIM + ct * 16 + cg * 4] = nh4;
      if (t == TDIM - 1) {
        const size_t OH = (size_t)BDIM * TDIM * HDIM;
        const size_t OC = OH + 2 * (size_t)BDIM * HDIM;
        *(f32x4*)&out[OH + (size_t)layer * BDIM * HDIM + (size_t)(bt * 16 + r) * HDIM + ct * 16 + cg * 4] = nh4;
        *(f32x4*)&out[OC + (size_t)layer * BDIM * HDIM + (size_t)(bt * 16 + r) * HDIM + ct * 16 + cg * 4] = nc4;
      }
      if (layer == 0 && t + 1 < TDIM) {
        const float4* xv = (const float4*)(x + (size_t)(bt * 16 + xr) * (TDIM * DDIM)
                                             + (size_t)(t + 1) * DDIM + xcb * 16);
        xp0 = xv[0]; xp1 = xv[1]; xp2 = xv[2]; xp3 = xv[3];
      }
    }
  }
}

extern "C" void kernel_launch(void* const* d_in, const int* in_sizes, int n_in,
                              void* d_out, int out_size, void* d_ws, size_t ws_size,
                              hipStream_t stream) {
  (void)in_sizes; (void)n_in; (void)out_size; (void)ws_size;
  const float* x     = (const float*)d_in[0];
  const float* w_ih0 = (const float*)d_in[1];
  const float* w_hh0 = (const float*)d_in[2];
  const float* b0    = (const float*)d_in[3];
  const float* w_ih1 = (const float*)d_in[4];
  const float* w_hh1 = (const float*)d_in[5];
  const float* b1    = (const float*)d_in[6];
  float* out = (float*)d_out;

  char* ws = (char*)d_ws;
  uint32* cnt0F = (uint32*)(ws + 0);       // [4][32]
  uint32* cnt1F = (uint32*)(ws + 512);     // [4][32]
  uint32* consF = (uint32*)(ws + 1024);    // [4][32] + zero spill region
  ushort_t* ring  = (ushort_t*)(ws + 8192);                 // [8][64][512] bf16 (512KB)
  ushort_t* h1buf = (ushort_t*)(ws + 8192 + 524288);        // [2][64][512] bf16 (128KB)

  hipMemsetAsync(ws, 0, 4096, stream);
  lstm_fused<<<dim3(256), dim3(256), 0, stream>>>(
      x, w_ih0, w_hh0, b0, w_ih1, w_hh1, b1, out,
      cnt0F, cnt1F, consF, ring, h1buf);
}

// Round 14
// 3518.995 us; speedup vs baseline: 1.3727x; 1.3727x over previous
//
#include <hip/hip_runtime.h>

#define BDIM 64
#define TDIM 1024
#define DDIM 256
#define HDIM 512
#define RING 8

typedef unsigned short ushort_t;
typedef unsigned int uint32;
typedef unsigned long long ull;
typedef __attribute__((ext_vector_type(8))) short short8;
typedef __attribute__((ext_vector_type(4))) float f32x4;

__device__ __forceinline__ ushort_t f2bf(float f) {
  union { float f; uint32 u; } v; v.f = f;
  uint32 u = v.u;
  return (ushort_t)((u + 0x7fffu + ((u >> 16) & 1u)) >> 16);
}

__device__ __forceinline__ short8 pack8(float4 a, float4 b) {
  short8 s;
  s[0] = (short)f2bf(a.x); s[1] = (short)f2bf(a.y);
  s[2] = (short)f2bf(a.z); s[3] = (short)f2bf(a.w);
  s[4] = (short)f2bf(b.x); s[5] = (short)f2bf(b.y);
  s[6] = (short)f2bf(b.z); s[7] = (short)f2bf(b.w);
  return s;
}

__device__ __forceinline__ ull pack4bf(f32x4 v) {
  return (ull)f2bf(v[0]) | ((ull)f2bf(v[1]) << 16)
       | ((ull)f2bf(v[2]) << 32) | ((ull)f2bf(v[3]) << 48);
}

__device__ __forceinline__ float sigm(float x) { return 1.0f / (1.0f + __expf(-x)); }
__device__ __forceinline__ float tanh_fast(float x) { return 1.0f - 2.0f / (__expf(2.0f * x) + 1.0f); }

__device__ __forceinline__ uint32 ld_sc1(uint32* p) {
  return __hip_atomic_load(p, __ATOMIC_RELAXED, __HIP_MEMORY_SCOPE_AGENT);
}
__device__ __forceinline__ void st_sc1(uint32* p, uint32 v) {
  __hip_atomic_store(p, v, __ATOMIC_RELAXED, __HIP_MEMORY_SCOPE_AGENT);
}
__device__ __forceinline__ void st_sc1_u64(ull* p, ull v) {
  __hip_atomic_store(p, v, __ATOMIC_RELAXED, __HIP_MEMORY_SCOPE_AGENT);
}
__device__ __forceinline__ ull ld_sc1_u64(const ull* p) {
  return __hip_atomic_load((ull*)p, __ATOMIC_RELAXED, __HIP_MEMORY_SCOPE_AGENT);
}

__device__ __forceinline__ void wave_poll_sc1(uint32* fl, uint32 tgt) {
  int it = 0;
  for (;;) {
    uint32 v = ld_sc1(fl);
    if (__all((int)(v >= tgt))) break;
    __builtin_amdgcn_s_sleep(1);
    if (++it > 60000) break;   // bounded: wrong beats hang
  }
  asm volatile("" ::: "memory");
}

// ---- fragment-major LDS layout (conflict-free MFMA reads, r10-proven) ----
__device__ __forceinline__ int frag_off(int row, int kf, int lg) {   // ushort units
  return kf * 512 + (((lg * 16 + row) ^ (kf & 7)) << 3);
}

// ---- r14: lane-permuted staging — conflict-free b64 writes ----
// element(lane s,h,wv; instr q): e2=s&1, kf=(q>>2)*8|((s>>1)&7), lg=h, row=wv*4+(q&3).
// Bank-pair = ((row^kf)&7)*2+e2: within a 16-lane quarter s=0..15 covers all 16
// pairs -> conflict-free. Global src offset L=row*128+kf*8+lg*2+e2: per-wave span
// is one contiguous 512B window (8 full sectors) -> coalescing preserved.
__device__ __forceinline__ void ds_stage(ushort_t* dst, int tid, const ull* v) {
  const int s = tid & 15, h = (tid >> 4) & 3, wvq = tid >> 6;
#pragma unroll
  for (int q = 0; q < 8; ++q) {
    const int row = wvq * 4 + (q & 3);
    const int kf  = ((q >> 2) << 3) | ((s >> 1) & 7);
    *(ull*)&dst[frag_off(row, kf, h) + (s & 1) * 4] = v[q];
  }
}

__device__ __forceinline__ void load_sc1_8(const ull* src, int tid, ull* v) {
  const int s = tid & 15, h = (tid >> 4) & 3, wvq = tid >> 6;
#pragma unroll
  for (int q = 0; q < 8; ++q) {
    const int row = wvq * 4 + (q & 3);
    const int kf  = ((q >> 2) << 3) | ((s >> 1) & 7);
    v[q] = ld_sc1_u64(src + row * 128 + kf * 8 + h * 2 + (s & 1));
  }
}

__global__ void __launch_bounds__(256, 1)
lstm_fused(const float* __restrict__ x,
           const float* __restrict__ w_ih0, const float* __restrict__ w_hh0,
           const float* __restrict__ b0,
           const float* __restrict__ w_ih1, const float* __restrict__ w_hh1,
           const float* __restrict__ b1,
           float* __restrict__ out,
           uint32* cnt0F, uint32* cnt1F, uint32* consF,
           ushort_t* ring, ushort_t* h1buf)
{
  const int b     = (int)blockIdx.x;
  const int g     = b & 7;
  const int layer = g >> 2;
  const int bt    = g & 3;
  const int ct    = b >> 3;
  const int tid   = (int)threadIdx.x;
  const int wv    = tid >> 6;
  const int lane  = tid & 63;
  const int lr    = lane & 15;
  const int lg    = lane >> 4;

  __shared__ __align__(16) ushort_t Is[16 * 512];   // fragment-major
  __shared__ __align__(16) ushort_t Hs[16 * 512];   // fragment-major
  __shared__ float gates[4][16][16];

  const int NI  = layer ? 16 : 8;
  const int Din = layer ? HDIM : DDIM;
  const float* wih = layer ? w_ih1 : w_ih0;
  const float* whh = layer ? w_hh1 : w_hh0;
  const float* bb  = layer ? b1 : b0;
  const int grow = wv * HDIM + ct * 16 + lr;

  short8 wf[32];
#pragma unroll
  for (int kf = 0; kf < 32; ++kf) wf[kf] = (short8)((short)0);
#pragma unroll
  for (int kf = 0; kf < 32; ++kf) {
    if (kf < NI + 16) {
      const float* src;
      if (kf < NI) src = wih + (size_t)grow * Din + (size_t)kf * 32 + lg * 8;
      else         src = whh + (size_t)grow * HDIM + (size_t)(kf - NI) * 32 + lg * 8;
      float4 a = *(const float4*)(src);
      float4 bq = *(const float4*)(src + 4);
      wf[kf] = pack8(a, bq);
    }
  }
  const float bias = bb[grow];

  const ull* ring_u  = (const ull*)ring;
  const ull* h1buf_u = (const ull*)h1buf;

  float c4[4] = {0.f, 0.f, 0.f, 0.f};     // wave0: 4 cell states
  float4 xp0, xp1, xp2, xp3;
  const int xr = tid >> 4;
  const int xcb = tid & 15;

  if (layer == 0) {
    const float4* xv = (const float4*)(x + (size_t)(bt * 16 + xr) * (TDIM * DDIM) + xcb * 16);
    xp0 = xv[0]; xp1 = xv[1]; xp2 = xv[2]; xp3 = xv[3];
  }

  for (int t = 0; t < TDIM; ++t) {
    // ---- P1: polls (r10 structure: one wave per flag set, throttled) ----
    if (layer == 0) {
      if (wv == 0) {
        if (t > 0) wave_poll_sc1(cnt0F + bt * 32 + (lane & 31), (uint32)t);
      } else if (wv == 1) {
        if (t >= RING) wave_poll_sc1(consF + bt * 32 + (lane & 31), (uint32)(t - RING + 1));
      }
    } else {
      if (wv == 0) {
        if (t > 0) wave_poll_sc1(cnt1F + bt * 32 + (lane & 31), (uint32)t);
      } else if (wv == 1) {
        wave_poll_sc1(cnt0F + bt * 32 + (lane & 31), (uint32)(t + 1));   // y0[t] ready
      }
    }
    __syncthreads();

    // ---- P2/P3: stage inputs ----
    if (layer == 0) {
      {  // x[t] from prefetch regs -> fragment-major chunks (~2-way max)
        const int c0 = xcb * 16;
        *(short8*)&Is[frag_off(xr, c0 >> 5, (c0 >> 3) & 3)] = pack8(xp0, xp1);
        const int c1 = c0 + 8;
        *(short8*)&Is[frag_off(xr, c1 >> 5, (c1 >> 3) & 3)] = pack8(xp2, xp3);
      }
      if (t > 0) {
        ull hv[8];
        load_sc1_8(ring_u + (size_t)((t - 1) & (RING - 1)) * 8192 + (size_t)bt * 2048, tid, hv);
        ds_stage(Hs, tid, hv);
      }
    } else {
      ull rv[8], hv[8];
      load_sc1_8(ring_u + (size_t)(t & (RING - 1)) * 8192 + (size_t)bt * 2048, tid, rv);
      if (t > 0)
        load_sc1_8(h1buf_u + (size_t)((t - 1) & 1) * 8192 + (size_t)bt * 2048, tid, hv);
      ds_stage(Is, tid, rv);
      if (t > 0) ds_stage(Hs, tid, hv);
    }
    __syncthreads();
    if (layer == 1 && tid == 0)
      st_sc1(consF + bt * 32 + ct, (uint32)(t + 1));   // ring slot consumed

    // ---- P5: MFMA (conflict-free fragment reads) ----
    f32x4 acc0 = {0.f, 0.f, 0.f, 0.f}, acc1 = {0.f, 0.f, 0.f, 0.f};
#pragma unroll
    for (int kf = 0; kf < 16; ++kf) {
      if (kf < NI) {
        const short8 af = *(const short8*)&Is[frag_off(lr, kf, lg)];
        if (kf & 1) acc1 = __builtin_amdgcn_mfma_f32_16x16x32_bf16(af, wf[kf], acc1, 0, 0, 0);
        else        acc0 = __builtin_amdgcn_mfma_f32_16x16x32_bf16(af, wf[kf], acc0, 0, 0, 0);
      }
    }
    if (t > 0) {
#pragma unroll
      for (int kf = 0; kf < 16; ++kf) {
        const short8 af = *(const short8*)&Hs[frag_off(lr, kf, lg)];
        if (kf & 1) acc1 = __builtin_amdgcn_mfma_f32_16x16x32_bf16(af, wf[NI + kf], acc1, 0, 0, 0);
        else        acc0 = __builtin_amdgcn_mfma_f32_16x16x32_bf16(af, wf[NI + kf], acc0, 0, 0, 0);
      }
    }
#pragma unroll
    for (int i = 0; i < 4; ++i) {
      float v = acc0[i] + acc1[i] + bias;
      float a = (wv < 3) ? sigm(v) : tanh_fast(v);
      gates[wv][lg * 4 + i][lr] = a;
    }
    __syncthreads();

    // ---- P6/P7: pointwise (wave0) + publish; others prefetch x ----
    if (layer == 0 && wv != 0 && t + 1 < TDIM) {
      const float4* xv = (const float4*)(x + (size_t)(bt * 16 + xr) * (TDIM * DDIM)
                                           + (size_t)(t + 1) * DDIM + xcb * 16);
      xp0 = xv[0]; xp1 = xv[1]; xp2 = xv[2]; xp3 = xv[3];
    }
    if (wv == 0) {
      const int r  = lane >> 2;
      const int cg = lane & 3;
      f32x4 gi = *(const f32x4*)&gates[0][r][cg * 4];
      f32x4 gf = *(const f32x4*)&gates[1][r][cg * 4];
      f32x4 go = *(const f32x4*)&gates[2][r][cg * 4];
      f32x4 gg = *(const f32x4*)&gates[3][r][cg * 4];
      f32x4 nh4, nc4;
#pragma unroll
      for (int k = 0; k < 4; ++k) {
        float nc = gf[k] * c4[k] + gi[k] * gg[k];
        float nh = go[k] * tanh_fast(nc);     // h uses UNCLIPPED c
        nc = fminf(fmaxf(nc, -50.f), 50.f);
        nh = fminf(fmaxf(nh, -50.f), 50.f);
        c4[k] = nc; nh4[k] = nh; nc4[k] = nc;
      }
      const ull hv = pack4bf(nh4);
      ull* dst;
      if (layer == 0)
        dst = (ull*)(ring_u + (size_t)(t & (RING - 1)) * 8192
                     + (size_t)(bt * 16 + r) * 128 + ct * 4 + cg);
      else
        dst = (ull*)(h1buf_u + (size_t)(t & 1) * 8192
                     + (size_t)(bt * 16 + r) * 128 + ct * 4 + cg);
      st_sc1_u64(dst, hv);
      asm volatile("s_waitcnt vmcnt(0)" ::: "memory");
      if (lane == 0) st_sc1((layer == 0 ? cnt0F : cnt1F) + bt * 32 + ct, (uint32)(t + 1));
      if (layer == 1)
        *(f32x4*)&out[(size_t)(bt * 16 + r) * (TDIM * HDIM) + (size_t)t * HDIM + ct * 16 + cg * 4] = nh4;
      if (t == TDIM - 1) {
        const size_t OH = (size_t)BDIM * TDIM * HDIM;
        const size_t OC = OH + 2 * (size_t)BDIM * HDIM;
        *(f32x4*)&out[OH + (size_t)layer * BDIM * HDIM + (size_t)(bt * 16 + r) * HDIM + ct * 16 + cg * 4] = nh4;
        *(f32x4*)&out[OC + (size_t)layer * BDIM * HDIM + (size_t)(bt * 16 + r) * HDIM + ct * 16 + cg * 4] = nc4;
      }
      if (layer == 0 && t + 1 < TDIM) {
        const float4* xv = (const float4*)(x + (size_t)(bt * 16 + xr) * (TDIM * DDIM)
                                             + (size_t)(t + 1) * DDIM + xcb * 16);
        xp0 = xv[0]; xp1 = xv[1]; xp2 = xv[2]; xp3 = xv[3];
      }
    }
  }
}

extern "C" void kernel_launch(void* const* d_in, const int* in_sizes, int n_in,
                              void* d_out, int out_size, void* d_ws, size_t ws_size,
                              hipStream_t stream) {
  (void)in_sizes; (void)n_in; (void)out_size; (void)ws_size;
  const float* x     = (const float*)d_in[0];
  const float* w_ih0 = (const float*)d_in[1];
  const float* w_hh0 = (const float*)d_in[2];
  const float* b0    = (const float*)d_in[3];
  const float* w_ih1 = (const float*)d_in[4];
  const float* w_hh1 = (const float*)d_in[5];
  const float* b1    = (const float*)d_in[6];
  float* out = (float*)d_out;

  char* ws = (char*)d_ws;
  uint32* cnt0F = (uint32*)(ws + 0);       // [4][32]
  uint32* cnt1F = (uint32*)(ws + 512);     // [4][32]
  uint32* consF = (uint32*)(ws + 1024);    // [4][32]
  ushort_t* ring  = (ushort_t*)(ws + 8192);                 // [8][64][512] bf16 (512KB)
  ushort_t* h1buf = (ushort_t*)(ws + 8192 + 524288);        // [2][64][512] bf16 (128KB)

  hipMemsetAsync(ws, 0, 4096, stream);
  lstm_fused<<<dim3(256), dim3(256), 0, stream>>>(
      x, w_ih0, w_hh0, b0, w_ih1, w_hh1, b1, out,
      cnt0F, cnt1F, consF, ring, h1buf);
}